// Round 10
// baseline (53.200 us; speedup 1.0000x reference)
//
#include <hip/hip_runtime.h>
#include <cmath>

#define CC_ 8
#define HH 512
#define WW 512
#define TW 32         // tile width
#define TH 32         // tile height
#define OHS 35        // onehot LDS stride in dwords
#define NWG ((WW/TW)*(HH/TH)*16)   // 16*16*16 = 4096
#define LOG2E 1.44269504088896340736f

__device__ __forceinline__ float comp4(const float4 v, int i){
  return (i==0)?v.x:((i==1)?v.y:((i==2)?v.z:v.w));
}

// fast bins + argmax with guarded bitwise-exact fallback (identical math to R9 pass)
__device__ __forceinline__ void px_bins(const float* l, unsigned int& bw_out, int& pc_out){
  float e[CC_]; float S = 0.f;
  #pragma unroll
  for (int c = 0; c < CC_; ++c){
    e[c] = __builtin_amdgcn_exp2f(l[c] * LOG2E);   // no max-subtract: |l| small
    S += e[c];
  }
  float b1 = e[0], b2 = 0.f; int pc = 0;
  #pragma unroll
  for (int c = 1; c < CC_; ++c){
    bool gt = e[c] > b1;
    b2 = gt ? b1 : fmaxf(b2, e[c]);
    pc = gt ? c : pc;
    b1 = gt ? e[c] : b1;
  }
  float r15 = 15.0f * __builtin_amdgcn_rcpf(S);
  unsigned int bw = 0;
  bool bad = (b1 - b2) < 1e-5f * b1;
  #pragma unroll
  for (int c = 0; c < CC_; ++c){
    float t = e[c] * r15;
    float rn = rintf(t);
    bad = bad || (rn > 0.5f && fabsf(t - rn) < 1e-4f);
    int b = (int)t; b = b > 14 ? 14 : b;
    bw |= (unsigned)b << (4*c);
  }
  if (bad){
    // exact reference path (bitwise anchor): max-subtract expf, IEEE divs
    float m = l[0];
    #pragma unroll
    for (int c = 1; c < CC_; ++c) m = fmaxf(m, l[c]);
    float ee[CC_]; float SS = 0.f;
    #pragma unroll
    for (int c = 0; c < CC_; ++c){ ee[c] = expf(l[c]-m); SS += ee[c]; }
    float p[CC_];
    #pragma unroll
    for (int c = 0; c < CC_; ++c) p[c] = ee[c]/SS;
    float best = p[0]; pc = 0;
    #pragma unroll
    for (int c = 1; c < CC_; ++c){ if (p[c] > best){ best = p[c]; pc = c; } }
    bw = 0;
    #pragma unroll
    for (int c = 0; c < CC_; ++c){
      int b = (int)(p[c]*15.0f); b = b > 14 ? 14 : b;
      bw |= (unsigned)b << (4*c);
    }
  }
  bw_out = bw; pc_out = pc;
}

__global__ __launch_bounds__(256, 4) void nectar_binning_kernel(
    const float* __restrict__ logits,
    const float* __restrict__ vf,
    float* __restrict__ out){
  __shared__ float s_vf[CC_*144];                  // [c][bin][nn]: c*144 + b*9 + nn
  __shared__ unsigned int s_oneh[(TH+2)*OHS];

  const int tid = threadIdx.x;

  // XCD-bijective swizzle: NWG%8==0, consecutive virt ids stay on one XCD
  const int lin  = blockIdx.x;
  const int virt = (lin & 7) * (NWG/8) + (lin >> 3);
  const int bz   = virt >> 8;            // 256 tiles per batch
  const int rem  = virt & 255;
  const int h0   = (rem >> 4) * TH;      // 16 tile-rows
  const int w0   = (rem & 15) * TW;      // 16 tile-cols
  const long base_b = (long)bz * (CC_*HH*WW);

  const int tx = tid & 7;                // w-quad (4 px)
  const int ty = tid >> 3;               // row 0..31

  // ---- issue ALL global loads up front: interior strip (8 x float4), then halo ----
  const int gw = w0 + 4*tx;
  const int gh = h0 + ty;
  const float* lp = logits + base_b + (long)gh*WW + gw;
  float4 lv[CC_];
  #pragma unroll
  for (int c = 0; c < CC_; ++c) lv[c] = *reinterpret_cast<const float4*>(lp + (long)c*(HH*WW));

  float hl[CC_]; bool hval = false; int hr = 0, hc = 0;
  if (tid < 132){
    int r, c;
    if      (tid < 34){ r = -1;       c = tid - 1;  }
    else if (tid < 68){ r = TH;       c = tid - 35; }
    else if (tid < 100){ r = tid-68;  c = -1;       }
    else               { r = tid-100; c = TW;       }
    hr = r; hc = c;
    const int hh = h0 + r, ww = w0 + c;
    hval = (hh >= 0 && hh < HH && ww >= 0 && ww < WW);
    const int hhc = min(max(hh,0),HH-1), wwc = min(max(ww,0),WW-1);
    const float* hp = logits + base_b + (long)hhc*WW + wwc;
    #pragma unroll
    for (int c2 = 0; c2 < CC_; ++c2) hl[c2] = hp[(long)c2*(HH*WW)];
  }

  // stage calibration table (LDS writes overlap load latency)
  for (int i = tid; i < CC_*9*15; i += 256){
    int b = i % 15, q = i / 15;
    int nn = q % 9, c = q / 9;
    s_vf[c*144 + b*9 + nn] = vf[i];
  }

  unsigned int binw[4];
  unsigned int ohv[4];     // own one-hot kept in registers (no LDS re-read)

  // ---- interior compute ----
  #pragma unroll
  for (int i = 0; i < 4; ++i){
    float l[CC_];
    #pragma unroll
    for (int c = 0; c < CC_; ++c) l[c] = comp4(lv[c], i);
    int pc; px_bins(l, binw[i], pc);
    unsigned int oh = 1u << (4*pc);
    ohv[i] = oh;
    s_oneh[(ty+1)*OHS + 4*tx + i + 1] = oh;
  }

  // ---- halo argmax (loads in flight since kernel top) ----
  if (tid < 132){
    unsigned int oh = 0u;
    if (hval){
      float b1 = hl[0], b2 = -1e30f; int pc = 0;
      #pragma unroll
      for (int c2 = 1; c2 < CC_; ++c2){
        bool gt = hl[c2] > b1;
        b2 = gt ? b1 : fmaxf(b2, hl[c2]);
        pc = gt ? c2 : pc;
        b1 = gt ? hl[c2] : b1;
      }
      if (b1 - b2 < 1e-5f){
        float e[CC_]; float S = 0.f;
        #pragma unroll
        for (int c2 = 0; c2 < CC_; ++c2){ e[c2] = expf(hl[c2]-b1); S += e[c2]; }
        float p[CC_];
        #pragma unroll
        for (int c2 = 0; c2 < CC_; ++c2) p[c2] = e[c2]/S;
        float best = p[0]; pc = 0;
        #pragma unroll
        for (int c2 = 1; c2 < CC_; ++c2){ if (p[c2] > best){ best = p[c2]; pc = c2; } }
      }
      oh = 1u << (4*pc);
    }
    s_oneh[(hr+1)*OHS + hc + 1] = oh;
  }

  __syncthreads();

  // ---- epilogue: 3x3 nibble histogram, BFI nn-transform, gather, normalize, store ----
  unsigned int cs[6];
  #pragma unroll
  for (int kk = 0; kk < 6; ++kk){
    int cidx = 4*tx + kk;
    cs[kk] = s_oneh[ ty   *OHS + cidx]
           + s_oneh[(ty+1)*OHS + cidx]
           + s_oneh[(ty+2)*OHS + cidx];
  }
  float4 o[CC_];
  #pragma unroll
  for (int i = 0; i < 4; ++i){
    unsigned int ctr = ohv[i];                        // 1 << 4*pc (registers)
    unsigned int acc = cs[i] + cs[i+1] + cs[i+2] - ctr;   // per-class neighbor counts
    unsigned int valid = (acc * 0x11111111u) >> 28;       // # valid neighbors (<=8)
    // nibble-parallel matching-count: nn_c = valid - cnt_c for c != pc, cnt_pc for c == pc
    unsigned int vw   = valid * 0x11111111u;              // broadcast valid to all nibbles
    unsigned int sub  = vw - acc;                         // borrow-free: cnt_c <= valid
    unsigned int mask = (ctr << 4) - ctr;                 // 0xF << 4*pc
    unsigned int nnw  = (acc & mask) | (sub & ~mask);     // v_bfi_b32
    unsigned int bw = binw[i];
    float v[CC_]; float S2 = 0.f;
    #pragma unroll
    for (int c = 0; c < CC_; ++c){
      unsigned int nn = (nnw >> (4*c)) & 0xFu;
      unsigned int b  = (bw  >> (4*c)) & 0xFu;
      float t = s_vf[c*144 + b*9 + nn];
      v[c] = t; S2 += t;
    }
    float r2 = 1.0f / S2;
    #pragma unroll
    for (int c = 0; c < CC_; ++c){
      float res = v[c]*r2;
      if(i==0) o[c].x = res; else if(i==1) o[c].y = res; else if(i==2) o[c].z = res; else o[c].w = res;
    }
  }
  // A/B vs R9: REGULAR stores (through L2, lazy writeback) instead of NT
  #pragma unroll
  for (int c = 0; c < CC_; ++c)
    *reinterpret_cast<float4*>(out + base_b + (long)c*(HH*WW) + (long)gh*WW + gw) = o[c];
}

extern "C" void kernel_launch(void* const* d_in, const int* in_sizes, int n_in,
                              void* d_out, int out_size, void* d_ws, size_t ws_size,
                              hipStream_t stream){
  const float* logits = (const float*)d_in[0];
  const float* vf     = (const float*)d_in[1];
  float* out          = (float*)d_out;
  nectar_binning_kernel<<<dim3(NWG), 256, 0, stream>>>(logits, vf, out);
}

// Round 11
// 50.221 us; speedup vs baseline: 1.0593x; 1.0593x over previous
//
#include <hip/hip_runtime.h>
#include <cmath>

#define CC_ 8
#define HH 512
#define WW 512
#define TW 32         // tile width
#define TH 32         // tile height
#define OHS 35        // onehot LDS stride in dwords
#define NWG ((WW/TW)*(HH/TH)*16)   // 16*16*16 = 4096
#define LOG2E 1.44269504088896340736f

typedef float vfloat4 __attribute__((ext_vector_type(4)));   // native vec for NT store

__device__ __forceinline__ float comp4(const float4 v, int i){
  return (i==0)?v.x:((i==1)?v.y:((i==2)?v.z:v.w));
}

// fast bins + argmax with guarded bitwise-exact fallback
__device__ __forceinline__ void px_bins(const float* l, unsigned int& bw_out, int& pc_out){
  float e[CC_]; float S = 0.f;
  #pragma unroll
  for (int c = 0; c < CC_; ++c){
    e[c] = __builtin_amdgcn_exp2f(l[c] * LOG2E);   // no max-subtract: |l| small
    S += e[c];
  }
  float b1 = e[0], b2 = 0.f; int pc = 0;
  #pragma unroll
  for (int c = 1; c < CC_; ++c){
    bool gt = e[c] > b1;
    b2 = gt ? b1 : fmaxf(b2, e[c]);
    pc = gt ? c : pc;
    b1 = gt ? e[c] : b1;
  }
  float r15 = 15.0f * __builtin_amdgcn_rcpf(S);
  unsigned int bw = 0;
  bool bad = (b1 - b2) < 1e-5f * b1;
  #pragma unroll
  for (int c = 0; c < CC_; ++c){
    float t = e[c] * r15;
    float rn = rintf(t);
    bad = bad || (rn > 0.5f && fabsf(t - rn) < 1e-4f);
    int b = (int)t; b = b > 14 ? 14 : b;
    bw |= (unsigned)b << (4*c);
  }
  if (bad){
    // exact reference path (bitwise anchor): max-subtract expf, IEEE divs
    float m = l[0];
    #pragma unroll
    for (int c = 1; c < CC_; ++c) m = fmaxf(m, l[c]);
    float ee[CC_]; float SS = 0.f;
    #pragma unroll
    for (int c = 0; c < CC_; ++c){ ee[c] = expf(l[c]-m); SS += ee[c]; }
    float p[CC_];
    #pragma unroll
    for (int c = 0; c < CC_; ++c) p[c] = ee[c]/SS;
    float best = p[0]; pc = 0;
    #pragma unroll
    for (int c = 1; c < CC_; ++c){ if (p[c] > best){ best = p[c]; pc = c; } }
    bw = 0;
    #pragma unroll
    for (int c = 0; c < CC_; ++c){
      int b = (int)(p[c]*15.0f); b = b > 14 ? 14 : b;
      bw |= (unsigned)b << (4*c);
    }
  }
  bw_out = bw; pc_out = pc;
}

__global__ __launch_bounds__(256, 4) void nectar_binning_kernel(
    const float* __restrict__ logits,
    const float* __restrict__ vf,
    float* __restrict__ out){
  __shared__ float s_vf[CC_*144];                  // [c][bin][nn]: c*144 + b*9 + nn
  __shared__ unsigned int s_oneh[(TH+2)*OHS];

  const int tid = threadIdx.x;

  // XCD-bijective swizzle: NWG%8==0, consecutive virt ids stay on one XCD
  const int lin  = blockIdx.x;
  const int virt = (lin & 7) * (NWG/8) + (lin >> 3);
  const int bz   = virt >> 8;            // 256 tiles per batch
  const int rem  = virt & 255;
  const int h0   = (rem >> 4) * TH;      // 16 tile-rows
  const int w0   = (rem & 15) * TW;      // 16 tile-cols
  const long base_b = (long)bz * (CC_*HH*WW);

  const int tx = tid & 7;                // w-quad (4 px)
  const int ty = tid >> 3;               // row 0..31

  // ---- issue ALL global loads up front: interior strip (8 x float4), then halo ----
  const int gw = w0 + 4*tx;
  const int gh = h0 + ty;
  const float* lp = logits + base_b + (long)gh*WW + gw;
  float4 lv[CC_];
  #pragma unroll
  for (int c = 0; c < CC_; ++c) lv[c] = *reinterpret_cast<const float4*>(lp + (long)c*(HH*WW));

  float hl[CC_]; bool hval = false; int hr = 0, hc = 0;
  if (tid < 132){
    int r, c;
    if      (tid < 34){ r = -1;       c = tid - 1;  }
    else if (tid < 68){ r = TH;       c = tid - 35; }
    else if (tid < 100){ r = tid-68;  c = -1;       }
    else               { r = tid-100; c = TW;       }
    hr = r; hc = c;
    const int hh = h0 + r, ww = w0 + c;
    hval = (hh >= 0 && hh < HH && ww >= 0 && ww < WW);
    const int hhc = min(max(hh,0),HH-1), wwc = min(max(ww,0),WW-1);
    const float* hp = logits + base_b + (long)hhc*WW + wwc;
    #pragma unroll
    for (int c2 = 0; c2 < CC_; ++c2) hl[c2] = hp[(long)c2*(HH*WW)];
  }

  // stage calibration table (LDS writes overlap load latency)
  for (int i = tid; i < CC_*9*15; i += 256){
    int b = i % 15, q = i / 15;
    int nn = q % 9, c = q / 9;
    s_vf[c*144 + b*9 + nn] = vf[i];
  }

  unsigned int binw[4];
  unsigned int ohv[4];     // own one-hot kept in registers (no LDS re-read)

  // ---- interior compute ----
  #pragma unroll
  for (int i = 0; i < 4; ++i){
    float l[CC_];
    #pragma unroll
    for (int c = 0; c < CC_; ++c) l[c] = comp4(lv[c], i);
    int pc; px_bins(l, binw[i], pc);
    unsigned int oh = 1u << (4*pc);
    ohv[i] = oh;
    s_oneh[(ty+1)*OHS + 4*tx + i + 1] = oh;
  }

  // ---- halo argmax (loads in flight since kernel top) ----
  if (tid < 132){
    unsigned int oh = 0u;
    if (hval){
      float b1 = hl[0], b2 = -1e30f; int pc = 0;
      #pragma unroll
      for (int c2 = 1; c2 < CC_; ++c2){
        bool gt = hl[c2] > b1;
        b2 = gt ? b1 : fmaxf(b2, hl[c2]);
        pc = gt ? c2 : pc;
        b1 = gt ? hl[c2] : b1;
      }
      if (b1 - b2 < 1e-5f){
        float e[CC_]; float S = 0.f;
        #pragma unroll
        for (int c2 = 0; c2 < CC_; ++c2){ e[c2] = expf(hl[c2]-b1); S += e[c2]; }
        float p[CC_];
        #pragma unroll
        for (int c2 = 0; c2 < CC_; ++c2) p[c2] = e[c2]/S;
        float best = p[0]; pc = 0;
        #pragma unroll
        for (int c2 = 1; c2 < CC_; ++c2){ if (p[c2] > best){ best = p[c2]; pc = c2; } }
      }
      oh = 1u << (4*pc);
    }
    s_oneh[(hr+1)*OHS + hc + 1] = oh;
  }

  __syncthreads();

  // ---- epilogue: 3x3 nibble histogram, BFI nn-transform, gather, normalize, NT store ----
  unsigned int cs[6];
  #pragma unroll
  for (int kk = 0; kk < 6; ++kk){
    int cidx = 4*tx + kk;
    cs[kk] = s_oneh[ ty   *OHS + cidx]
           + s_oneh[(ty+1)*OHS + cidx]
           + s_oneh[(ty+2)*OHS + cidx];
  }
  float4 o[CC_];
  #pragma unroll
  for (int i = 0; i < 4; ++i){
    unsigned int ctr = ohv[i];                        // 1 << 4*pc (registers)
    unsigned int acc = cs[i] + cs[i+1] + cs[i+2] - ctr;   // per-class neighbor counts
    unsigned int valid = (acc * 0x11111111u) >> 28;       // # valid neighbors (<=8)
    // nibble-parallel matching-count: nn_c = valid - cnt_c for c != pc, cnt_pc for c == pc
    unsigned int vw   = valid * 0x11111111u;              // broadcast valid to all nibbles
    unsigned int sub  = vw - acc;                         // borrow-free: cnt_c <= valid
    unsigned int mask = (ctr << 4) - ctr;                 // 0xF << 4*pc
    unsigned int nnw  = (acc & mask) | (sub & ~mask);     // v_bfi_b32
    unsigned int bw = binw[i];
    float v[CC_]; float S2 = 0.f;
    #pragma unroll
    for (int c = 0; c < CC_; ++c){
      unsigned int nn = (nnw >> (4*c)) & 0xFu;
      unsigned int b  = (bw  >> (4*c)) & 0xFu;
      float t = s_vf[c*144 + b*9 + nn];
      v[c] = t; S2 += t;
    }
    float r2 = 1.0f / S2;
    #pragma unroll
    for (int c = 0; c < CC_; ++c){
      float res = v[c]*r2;
      if(i==0) o[c].x = res; else if(i==1) o[c].y = res; else if(i==2) o[c].z = res; else o[c].w = res;
    }
  }
  #pragma unroll
  for (int c = 0; c < CC_; ++c){
    vfloat4 nv = { o[c].x, o[c].y, o[c].z, o[c].w };
    __builtin_nontemporal_store(nv,
      reinterpret_cast<vfloat4*>(out + base_b + (long)c*(HH*WW) + (long)gh*WW + gw));
  }
}

extern "C" void kernel_launch(void* const* d_in, const int* in_sizes, int n_in,
                              void* d_out, int out_size, void* d_ws, size_t ws_size,
                              hipStream_t stream){
  const float* logits = (const float*)d_in[0];
  const float* vf     = (const float*)d_in[1];
  float* out          = (float*)d_out;
  nectar_binning_kernel<<<dim3(NWG), 256, 0, stream>>>(logits, vf, out);
}